// Round 1
// 878.475 us; speedup vs baseline: 1.0857x; 1.0857x over previous
//
#include <hip/hip_runtime.h>
#include <stdint.h>

#define T_STEPS 512
#define F_IN 30
#define HID 32
#define ROWS 16   // batch rows per block (one MFMA M-tile)
#define LOG2E 1.44269504088896340736f

typedef __attribute__((ext_vector_type(8))) short short8;   // 8 bf16 (4 VGPRs)
typedef __attribute__((ext_vector_type(4))) float floatx4;  // 4 f32 acc

#define MFMA(a, b, c) __builtin_amdgcn_mfma_f32_16x16x32_bf16((a), (b), (c), 0, 0, 0)

// Raw barrier: drain LDS only (lgkmcnt), let global loads/stores ride across.
#define BAR() asm volatile("s_waitcnt lgkmcnt(0)\n\ts_barrier" ::: "memory")

__device__ __forceinline__ unsigned short f2bf(float f) {
    uint32_t u = __float_as_uint(f);
    u += 0x7fffu + ((u >> 16) & 1u);            // RTNE
    return (unsigned short)(u >> 16);
}
__device__ __forceinline__ float bf2f(unsigned short h) {
    return __uint_as_float(((uint32_t)h) << 16);
}
// packed f32->bf16 RTNE, single VALU op (gfx950)
__device__ __forceinline__ uint32_t cvtpk(float a, float b) {
    uint32_t r;
    asm("v_cvt_pk_bf16_f32 %0, %1, %2" : "=v"(r) : "v"(a), "v"(b));
    return r;
}
__device__ __forceinline__ float rcp_f(float x) { return __builtin_amdgcn_rcpf(x); }

__device__ __forceinline__ void loadx8(float (&d)[8], const float* p, bool tail) {
    float2 a0 = *(const float2*)(p + 0);
    float2 a1 = *(const float2*)(p + 2);
    float2 a2 = *(const float2*)(p + 4);
    float2 a3 = make_float2(0.f, 0.f);
    if (!tail) a3 = *(const float2*)(p + 6);     // quad3 covers features 24..29 + zero pad
    d[0]=a0.x; d[1]=a0.y; d[2]=a1.x; d[3]=a1.y;
    d[4]=a2.x; d[5]=a2.y; d[6]=a3.x; d[7]=a3.y;
}

__global__ __launch_bounds__(512, 1)
void lstm_fused_kernel(const float* __restrict__ x, const float* __restrict__ h0,
                       const float* __restrict__ c0, const float* __restrict__ W_ih,
                       const float* __restrict__ W_hh, const float* __restrict__ b_ih,
                       const float* __restrict__ b_hh, const float* __restrict__ W_all,
                       const float* __restrict__ b_all, const float* __restrict__ W_pos,
                       const float* __restrict__ b_pos, const float* __restrict__ W_lv,
                       const float* __restrict__ b_lv, float* __restrict__ pos_out,
                       float* __restrict__ lv_out, float* __restrict__ hT_out,
                       float* __restrict__ cT_out)
{
    const int tid  = threadIdx.x;
    const int wv   = tid >> 6;        // wave 0..7 == n-tile; gate type = wv>>1
    const int lane = tid & 63;
    const int quad = lane >> 4;
    const int l15  = lane & 15;
    const int rowbase = blockIdx.x * ROWS;

    __shared__ float gbuf[ROWS][132];                        // [row][gate 0..127], +4 pad
    // h state, bf16 hi/lo in SEPARATE arrays -> ds_read_b128 gives MFMA frags with ZERO unpack.
    // row stride 40 ushorts = 80 B (16B-aligned rows; b128 reads spread uniformly over banks)
    __shared__ __align__(16) unsigned short hbh[ROWS][40];
    __shared__ __align__(16) unsigned short hbl[ROWS][40];
    // masked output (out = m ? h_new : 0) hi/lo: A-operand of the head MFMA
    __shared__ __align__(16) unsigned short obh[ROWS][40];
    __shared__ __align__(16) unsigned short obl[ROWS][40];

    // ---- B-fragments for this wave's n-tile (gate column gcol) ----
    // exp2 folding: scale W and bias by -log2e (sigmoid gates) / -2*log2e (g gate),
    // so activation = rcp(1+exp2(acc)) (resp. fma(2,rcp,-1)) with NO fp32 division.
    const bool  is_g   = ((wv >> 1) == 2);
    const float gscale = (is_g ? -2.0f : -1.0f) * LOG2E;
    const int gcol = wv * 16 + l15;
    short8 wxh, wxl, whh, whl;
#pragma unroll
    for (int j = 0; j < 8; ++j) {
        const int k = quad * 8 + j;
        float wx = (k < F_IN) ? W_ih[gcol * F_IN + k] * gscale : 0.0f;
        unsigned short hx = f2bf(wx);
        wxh[j] = (short)hx; wxl[j] = (short)f2bf(wx - bf2f(hx));
        float wh = W_hh[gcol * HID + k] * gscale;
        unsigned short hh = f2bf(wh);
        whh[j] = (short)hh; whl[j] = (short)f2bf(wh - bf2f(hh));
    }
    const float bias = (b_ih[gcol] + b_hh[gcol]) * gscale;

    // ---- head B-fragments (used by wave 0): col 0 = pos0, 1 = pos1, 2 = leave ----
    // Wc[g][k] = sum_o W_pos[g][o] * W_all[o][k]  (hi/lo split for fp32-grade dot)
    short8 wph, wpl;
#pragma unroll
    for (int j = 0; j < 8; ++j) {
        const int k = quad * 8 + j;
        float w = 0.0f;
        if (l15 == 0) { for (int o = 0; o < HID; ++o) w += W_pos[o] * W_all[o * HID + k]; }
        else if (l15 == 1) { for (int o = 0; o < HID; ++o) w += W_pos[HID + o] * W_all[o * HID + k]; }
        else if (l15 == 2) { w = W_lv[k]; }
        unsigned short hw_ = f2bf(w);
        wph[j] = (short)hw_; wpl[j] = (short)f2bf(w - bf2f(hw_));
    }
    float bc0 = b_pos[0], bc1 = b_pos[1];
    for (int o = 0; o < HID; ++o) { bc0 += W_pos[o] * b_all[o]; bc1 += W_pos[HID + o] * b_all[o]; }
    const float blv = b_lv[0];

    // ---- update role: thread = (row um, hidden unit uj) ----
    const int um = tid >> 5;          // 0..15
    const int uj = tid & 31;          // 0..31
    const int urow = rowbase + um;
    float c_st = c0[(size_t)urow * HID + uj];
    float h_st = h0[(size_t)urow * HID + uj];

    {   // init LDS state
        unsigned short ph = f2bf(h_st);
        hbh[um][uj] = ph;
        hbl[um][uj] = f2bf(h_st - bf2f(ph));
        obh[um][uj] = 0; obl[um][uj] = 0;
    }

    // x A-fragment pointers: lane (l15,quad) reads row rowbase+l15, feat quad*8..+7
    const float* xlane = x + (size_t)(rowbase + l15) * T_STEPS * F_IN + quad * 8;
    const float* mptr  = x + (size_t)urow * T_STEPS * F_IN + (F_IN - 1);
    const bool tail = (quad == 3);

    // depth-4 register prefetch ring
    float xr0[8], xr1[8], xr2[8], xr3[8];
    float mr0, mr1, mr2, mr3;
    loadx8(xr0, xlane + 0 * F_IN, tail);  mr0 = mptr[0 * F_IN];
    loadx8(xr1, xlane + 1 * F_IN, tail);  mr1 = mptr[1 * F_IN];
    loadx8(xr2, xlane + 2 * F_IN, tail);  mr2 = mptr[2 * F_IN];
    loadx8(xr3, xlane + 3 * F_IN, tail);  mr3 = mptr[3 * F_IN];

    BAR();

    auto step = [&](int t, float (&xr)[8], float& mr) {
        // snapshot mask before the ring slot is overwritten
        const float mcur = mr;
        // convert current x via packed bf16 cvt (4 ops instead of 8 manual RTNEs)
        union XU { uint32_t u[4]; short8 s; } xu;
        xu.u[0] = cvtpk(xr[0], xr[1]);
        xu.u[1] = cvtpk(xr[2], xr[3]);
        xu.u[2] = cvtpk(xr[4], xr[5]);
        xu.u[3] = cvtpk(xr[6], xr[7]);
        const short8 xah = xu.s;
        // h fragments: direct b128 reads, no unpack
        const short8 hah = *(const short8*)&hbh[l15][quad * 8];
        const short8 hal = *(const short8*)&hbl[l15][quad * 8];
        // wave0: issue head (t-1) operand reads early so latency hides under gate MFMAs
        const bool do_head = (wv == 0) && (t > 0);
        short8 oah, oal;
        if (do_head) {
            oah = *(const short8*)&obh[l15][quad * 8];
            oal = *(const short8*)&obl[l15][quad * 8];
        }
        // prefetch t+4 into this ring slot (rides across raw barriers)
        {
            const int tp = (t + 4 < T_STEPS) ? t + 4 : (T_STEPS - 1);
            loadx8(xr, xlane + tp * F_IN, tail);
            mr = mptr[tp * F_IN];
        }
        // two independent MFMA chains (depth 3 instead of 5), re-joined at activation
        floatx4 accx = {bias, bias, bias, bias};
        accx = MFMA(xah, wxh, accx);
        accx = MFMA(xah, wxl, accx);
        floatx4 acch = {0.f, 0.f, 0.f, 0.f};
        acch = MFMA(hah, whh, acch);
        acch = MFMA(hal, whh, acch);
        acch = MFMA(hah, whl, acch);
        // activation: rcp + hw exp2 (no fp32 division), scatter to gate buffer
#pragma unroll
        for (int r = 0; r < 4; ++r) {
            const float a  = accx[r] + acch[r];
            const float rr = rcp_f(1.0f + exp2f(a));
            gbuf[quad * 4 + r][gcol] = is_g ? fmaf(2.0f, rr, -1.0f) : rr;
        }
        // wave0: heads for step t-1 (one 16x16 tile covers all 16 rows; 3 MFMAs hi/lo)
        if (do_head) {
            floatx4 hacc = {0.f, 0.f, 0.f, 0.f};
            hacc = MFMA(oah, wph, hacc);
            hacc = MFMA(oal, wph, hacc);
            hacc = MFMA(oah, wpl, hacc);
            const size_t rb = (size_t)(rowbase + quad * 4) * T_STEPS + (t - 1);
            if (l15 == 0) {
#pragma unroll
                for (int r = 0; r < 4; ++r) pos_out[(rb + (size_t)r * T_STEPS) * 2 + 0] = hacc[r] + bc0;
            } else if (l15 == 1) {
#pragma unroll
                for (int r = 0; r < 4; ++r) pos_out[(rb + (size_t)r * T_STEPS) * 2 + 1] = hacc[r] + bc1;
            } else if (l15 == 2) {
#pragma unroll
                for (int r = 0; r < 4; ++r) {
                    const float z = hacc[r] + blv;
                    lv_out[rb + (size_t)r * T_STEPS] = rcp_f(1.0f + exp2f(-LOG2E * z));
                }
            }
        }
        BAR();
        // ---- state update: thread = (um, uj) ----
        const float gi = gbuf[um][uj];
        const float gf = gbuf[um][32 + uj];
        const float gg = gbuf[um][64 + uj];
        const float go = gbuf[um][96 + uj];
        const float cn = gf * c_st + gi * gg;
        const float tn = fmaf(2.0f, rcp_f(1.0f + exp2f(-2.0f * LOG2E * cn)), -1.0f);
        const float hn = go * tn;
        const bool  on = (mcur == 1.0f);
        const uint32_t hi32 = cvtpk(hn, hn);
        const float res = hn - bf2f((unsigned short)hi32);
        const uint32_t lo32 = cvtpk(res, res);
        // out tile (masked h) always written; h state only when mask fires
        obh[um][uj] = on ? (unsigned short)hi32 : (unsigned short)0;
        obl[um][uj] = on ? (unsigned short)lo32 : (unsigned short)0;
        if (on) {
            c_st = cn; h_st = hn;
            hbh[um][uj] = (unsigned short)hi32;
            hbl[um][uj] = (unsigned short)lo32;
        }
        BAR();
    };

    for (int t = 0; t < T_STEPS; t += 4) {
        step(t + 0, xr0, mr0);
        step(t + 1, xr1, mr1);
        step(t + 2, xr2, mr2);
        step(t + 3, xr3, mr3);
    }

    // epilogue: heads for the final step (t = T_STEPS-1)
    if (wv == 0) {
        const short8 oah = *(const short8*)&obh[l15][quad * 8];
        const short8 oal = *(const short8*)&obl[l15][quad * 8];
        floatx4 hacc = {0.f, 0.f, 0.f, 0.f};
        hacc = MFMA(oah, wph, hacc);
        hacc = MFMA(oal, wph, hacc);
        hacc = MFMA(oah, wpl, hacc);
        const size_t rb = (size_t)(rowbase + quad * 4) * T_STEPS + (T_STEPS - 1);
        if (l15 == 0) {
#pragma unroll
            for (int r = 0; r < 4; ++r) pos_out[(rb + (size_t)r * T_STEPS) * 2 + 0] = hacc[r] + bc0;
        } else if (l15 == 1) {
#pragma unroll
            for (int r = 0; r < 4; ++r) pos_out[(rb + (size_t)r * T_STEPS) * 2 + 1] = hacc[r] + bc1;
        } else if (l15 == 2) {
#pragma unroll
            for (int r = 0; r < 4; ++r) {
                const float z = hacc[r] + blv;
                lv_out[rb + (size_t)r * T_STEPS] = rcp_f(1.0f + exp2f(-LOG2E * z));
            }
        }
    }

    hT_out[(size_t)urow * HID + uj] = h_st;
    cT_out[(size_t)urow * HID + uj] = c_st;
}

extern "C" void kernel_launch(void* const* d_in, const int* in_sizes, int n_in,
                              void* d_out, int out_size, void* d_ws, size_t ws_size,
                              hipStream_t stream) {
    const float* x     = (const float*)d_in[0];
    const float* h0    = (const float*)d_in[1];
    const float* c0    = (const float*)d_in[2];
    const float* W_ih  = (const float*)d_in[3];
    const float* W_hh  = (const float*)d_in[4];
    const float* b_ih  = (const float*)d_in[5];
    const float* b_hh  = (const float*)d_in[6];
    const float* W_all = (const float*)d_in[7];
    const float* b_all = (const float*)d_in[8];
    const float* W_pos = (const float*)d_in[9];
    const float* b_pos = (const float*)d_in[10];
    const float* W_lv  = (const float*)d_in[11];
    const float* b_lv  = (const float*)d_in[12];

    const int B = in_sizes[1] / HID;         // h0 is [1,B,H] -> 4096
    float* out     = (float*)d_out;
    float* pos_out = out;                                    // [B,T,2]
    float* lv_out  = pos_out + (size_t)B * T_STEPS * 2;      // [B,T,1]
    float* hT_out  = lv_out  + (size_t)B * T_STEPS;          // [1,B,H]
    float* cT_out  = hT_out  + (size_t)B * HID;              // [1,B,H]

    dim3 grid(B / ROWS), block(512);
    hipLaunchKernelGGL(lstm_fused_kernel, grid, block, 0, stream,
                       x, h0, c0, W_ih, W_hh, b_ih, b_hh, W_all, b_all,
                       W_pos, b_pos, W_lv, b_lv, pos_out, lv_out, hT_out, cT_out);
}